// Round 8
// baseline (5867.833 us; speedup 1.0000x reference)
//
#include <hip/hip_runtime.h>

// VQ argmin: exact bit-level emulation of numpy fp32 reference:
//   A  = np.sum(flat*flat, axis=1)     (numpy pairwise-sum tree, fp32)
//   M2 = (2*flat) @ emb.T              (BLAS: sequential fp32 fma chain over d)
//   dist = (A - M2) + ee;  argmin_k (first-min ties)
// out: int32 [65536]
//
// R8: lane roles swapped. k lives across lanes (k = 256*kq + 64*q + lane):
// e feed = ONE coalesced global_load_dwordx4 per dd per wave (vmcnt pipe,
// proven to stream). z is wave-uniform AND contiguous in the native layout
// (16 consecutive n at fixed d = 64 B) -> ONE s_load_dwordx16 per dd per
// wave, ping-ponged (16+16 SGPR fits the 102 budget -- the reason R3/R4's
// KT=64 SMEM stream could NOT double-buffer). acc = 16n x 4q = 64 floats
// (the proven no-spill regime). Block 512 thr = 2 n-halves x 4 k-quarters
// = 32 n x all 1024 k: no cross-block k-split, single barrier, direct out.

#define D_DIM  256
#define K_DIM  1024
#define HW     4096
#define N_TOT  65536
#define NT     32     // n per block

// ---- fused prep: [0,1024) pack ept2; [1024,1028) ee; [1028,1284) A

__global__ void prep_kernel(const float* __restrict__ e, const float* __restrict__ z,
                            float* __restrict__ ept2, float* __restrict__ ee,
                            float* __restrict__ A) {
#pragma clang fp contract(off)
    const int bid = blockIdx.x;
    const int tid = threadIdx.x;

    if (bid < 1024) {
        // ept2[((kq*256 + d)*64 + l)*4 + q] = 2*emb[k][d], k = 256*kq + 64*q + l
        // x2 exact (exponent shift); z*(2e) == (2z)*e bitwise.
        const int k = bid, d = tid;
        const int kq = k >> 8, q = (k >> 6) & 3, l = k & 63;
        ept2[(((size_t)kq * D_DIM + d) * 64 + l) * 4 + q] = 2.0f * e[(size_t)k * D_DIM + d];
        return;
    }
    if (bid < 1028) {
        // ee[k]: numpy pairwise tree (two 128-blocks of 8 interleaved accs)
        const int k = (bid - 1024) * 256 + tid;
        const float* row = e + (size_t)k * D_DIM;
        float total = 0.0f;
        #pragma unroll
        for (int h = 0; h < 2; ++h) {
            const float* a = row + h * 128;
            float r[8];
            #pragma unroll
            for (int j = 0; j < 8; ++j) { float v = a[j]; r[j] = v * v; }
            #pragma unroll
            for (int i = 8; i < 128; i += 8) {
                #pragma unroll
                for (int j = 0; j < 8; ++j) { float v = a[i + j]; r[j] = r[j] + v * v; }
            }
            float s = ((r[0] + r[1]) + (r[2] + r[3])) + ((r[4] + r[5]) + (r[6] + r[7]));
            total = (h == 0) ? s : (total + s);
        }
        ee[k] = total;
        return;
    }
    {
        // A[n]: same tree over z (native strided layout)
        const int n = (bid - 1028) * 256 + tid;
        const float* base = z + (size_t)(n >> 12) * D_DIM * HW + (n & (HW - 1));
        float total = 0.0f;
        #pragma unroll
        for (int h = 0; h < 2; ++h) {
            float r[8];
            #pragma unroll
            for (int j = 0; j < 8; ++j) {
                float v = base[(size_t)(h * 128 + j) * HW];
                r[j] = v * v;
            }
            #pragma unroll
            for (int i = 8; i < 128; i += 8) {
                #pragma unroll
                for (int j = 0; j < 8; ++j) {
                    float v = base[(size_t)(h * 128 + i + j) * HW];
                    r[j] = r[j] + v * v;
                }
            }
            float s = ((r[0] + r[1]) + (r[2] + r[3])) + ((r[4] + r[5]) + (r[6] + r[7]));
            total = (h == 0) ? s : (total + s);
        }
        A[n] = total;
    }
}

// ---- main: 32 n x 1024 k per block; z via SMEM dwordx16, e via lane dwordx4

__launch_bounds__(512, 4)
__global__ void vq_main(const float* __restrict__ z, const float* __restrict__ ept2,
                        const float* __restrict__ A, const float* __restrict__ ee,
                        int* __restrict__ out) {
#pragma clang fp contract(off)
    __shared__ unsigned long long cvk[2][4][16];   // [nh][kq][i]

    const int tid = threadIdx.x;
    const int l   = tid & 63;
    const int w   = tid >> 6;        // 0..7
    const int kq  = w & 3;           // k-quarter (wave-uniform)
    const int nh  = w >> 2;          // n-half   (wave-uniform)
    const int nt  = blockIdx.x * NT; // 32 | 4096: tile never crosses batch
    const int bb  = nt >> 12;
    const int hw0 = nt & (HW - 1);

    // z row for this wave's 16 n at given d: 64 B contiguous, 64-B aligned
    const float* __restrict__ zrow = z + (size_t)bb * D_DIM * HW + hw0 + nh * 16;
    // e float4 for (d, lane): component q <-> k = 256*kq + 64*q + l
    const float4* __restrict__ e4 = (const float4*)ept2 + (size_t)kq * D_DIM * 64 + l;

    float acc[16][4];
    #pragma unroll
    for (int i = 0; i < 16; ++i)
        #pragma unroll
        for (int q = 0; q < 4; ++q) acc[i][q] = 0.0f;

    // software pipeline: distance-1 ping-pong on both operand streams
    float  zA[16], zB[16];
    float4 eA, eB;
    #pragma unroll
    for (int i = 0; i < 16; ++i) {
        zA[i] = zrow[i];                       // d=0 (uniform -> s_load, merged x16)
        zB[i] = zrow[(size_t)HW + i];          // d=1
    }
    eA = e4[0];
    eB = e4[64];

    #pragma unroll 2
    for (int d = 0; d < D_DIM; d += 2) {
        float  zC[16], zD[16];
        float4 eC, eD;
        const bool pf = (d < D_DIM - 2);
        if (pf) {
            #pragma unroll
            for (int i = 0; i < 16; ++i) {
                zC[i] = zrow[(size_t)(d + 2) * HW + i];
                zD[i] = zrow[(size_t)(d + 3) * HW + i];
            }
            eC = e4[(size_t)(d + 2) * 64];
            eD = e4[(size_t)(d + 3) * 64];
        }
        // compute d (zA,eA) then d+1 (zB,eB); per-acc chain order is
        // dependence-forced: strictly ascending d. 128 fma per iter.
        #pragma unroll
        for (int i = 0; i < 16; ++i) {
            const float zv = zA[i];
            acc[i][0] = fmaf(zv, eA.x, acc[i][0]);
            acc[i][1] = fmaf(zv, eA.y, acc[i][1]);
            acc[i][2] = fmaf(zv, eA.z, acc[i][2]);
            acc[i][3] = fmaf(zv, eA.w, acc[i][3]);
        }
        #pragma unroll
        for (int i = 0; i < 16; ++i) {
            const float zv = zB[i];
            acc[i][0] = fmaf(zv, eB.x, acc[i][0]);
            acc[i][1] = fmaf(zv, eB.y, acc[i][1]);
            acc[i][2] = fmaf(zv, eB.z, acc[i][2]);
            acc[i][3] = fmaf(zv, eB.w, acc[i][3]);
        }
        if (pf) {
            #pragma unroll
            for (int i = 0; i < 16; ++i) { zA[i] = zC[i]; zB[i] = zD[i]; }
            eA = eC; eB = eD;
        }
    }

    // epilogue: dist = (An - M2) + ee; pack (distbits<<32)|k -> u64 lex-min.
    // dist > 0 always -> IEEE bit order == value order; low word = k ->
    // u64 min == (min dist, ties -> lowest k) == numpy first-min.
    float An_[16];
    #pragma unroll
    for (int i = 0; i < 16; ++i) An_[i] = A[nt + nh * 16 + i];   // uniform
    float ee_[4];
    #pragma unroll
    for (int q = 0; q < 4; ++q) ee_[q] = ee[kq * 256 + 64 * q + l];

    #pragma unroll
    for (int i = 0; i < 16; ++i) {
        unsigned long long p = ~0ULL;
        #pragma unroll
        for (int q = 0; q < 4; ++q) {
            const float dist = (An_[i] - acc[i][q]) + ee_[q];
            const unsigned long long c =
                ((unsigned long long)__float_as_uint(dist) << 32)
                | (unsigned)(kq * 256 + 64 * q + l);
            if (c < p) p = c;
        }
        // 64-lane butterfly u64 min (order-independent; lex total order)
        #pragma unroll
        for (int off = 32; off >= 1; off >>= 1) {
            const unsigned long long o = __shfl_xor((unsigned long long)p, off, 64);
            if (o < p) p = o;
        }
        if (l == 0) cvk[nh][kq][i] = p;
    }
    __syncthreads();
    if (tid < 32) {
        const int nh2 = tid >> 4, i = tid & 15;
        unsigned long long b = cvk[nh2][0][i];
        #pragma unroll
        for (int kq2 = 1; kq2 < 4; ++kq2) {
            const unsigned long long v = cvk[nh2][kq2][i];
            if (v < b) b = v;
        }
        out[nt + nh2 * 16 + i] = (int)(unsigned)(b & 0xffffffffULL);
    }
}

extern "C" void kernel_launch(void* const* d_in, const int* in_sizes, int n_in,
                              void* d_out, int out_size, void* d_ws, size_t ws_size,
                              hipStream_t stream) {
    const float* z   = (const float*)d_in[0];   // [16,256,64,64]
    const float* emb = (const float*)d_in[1];   // [1024,256]
    int* out = (int*)d_out;                     // [65536] int32

    float* wsEPT = (float*)d_ws;                // 262144 floats (1 MB)
    float* wsEE  = wsEPT + (size_t)D_DIM * K_DIM;   // 1024
    float* wsA   = wsEE + K_DIM;                    // 65536

    prep_kernel<<<1284, 256, 0, stream>>>(emb, z, wsEPT, wsEE, wsA);
    vq_main<<<N_TOT / NT, 512, 0, stream>>>(z, wsEPT, wsA, wsEE, out);
}